// Round 7
// baseline (10090.169 us; speedup 1.0000x reference)
//
#include <hip/hip_runtime.h>
#include <hip/hip_bf16.h>

// ---------------------------------------------------------------------------
// CFODE: bi-GRU encoder/decoder -> latent SDE (140 Euler steps, 3-layer MLP
// drift with tanh+LayerNorm) -> decoder head.
//
// Round 7: exchange-free k_sde with correct arithmetic.
//  * 64 WGs x 1024 threads, 2 batch rows/WG. Each WG streams all MLP weights
//    (1.05 MB bf16) from L2 every step. No cross-WG dependencies at all.
//  * k_wprep: one-time transpose to k-major Wt[k][col] (bf16) in ws ->
//    wave-instant weight loads are 8 lanes x 8B = full 64B lines (no L1
//    reuse needed). Also precomputes LN-fold constants SwgB/btB/SwgC/btC.
//  * Thread = (col-quad, k-slice ks). k-reduce via shfl_xor. LDS activation
//    broadcasts staggered per-ks so concurrent addresses hit distinct banks.
//  * LN affine folded (validated rounds 5/6): bufs hold g*tanh, stats from
//    raw tanh, layer-2 affine applied inline in the Euler update.
// ---------------------------------------------------------------------------

#define EPS    1e-5f
#define DT_    0.05f
#define SQDT_  0.22360680997371674f   // sqrt(0.05)
#define SIG_   0.5f

#define NB    128
#define NLH   64
#define NLP   8
#define NSTEP 140
#define NSUB  20

// ws layout (float offsets). End ~592K floats (~2.37 MB).
#define WSH_OFF   0           // [128 rows][4 which][128]      = 65536
#define YS_OFF    65536       // [128 rows][8 samples][257]    = 263168
#define WT0_OFF   328704      // Wt0 [256][512] bf16           = 65536 fl
#define WT1_OFF   394240      // Wt1 [512][512] bf16           = 131072 fl
#define WT2_OFF   525312      // Wt2 [512][256] bf16           = 65536 fl
#define SWGB_OFF  590848      // [512] f32
#define BTB_OFF   591360      // [512] f32
#define SWGC_OFF  591872      // [256] f32
#define BTC_OFF   592128      // [256] f32

__device__ __forceinline__ float bf2f(unsigned short u) {
  return __uint_as_float(((unsigned)u) << 16);
}
__device__ __forceinline__ void up2(unsigned u, float* d) {
  d[0] = bf2f((unsigned short)(u & 0xffff));
  d[1] = bf2f((unsigned short)(u >> 16));
}
__device__ __forceinline__ float ldv(const void* p, int i, bool bf) {
  return bf ? bf2f(((const unsigned short*)p)[i]) : ((const float*)p)[i];
}
__device__ __forceinline__ void st_out(void* p, int i, float v, bool bf) {
  if (bf) ((__hip_bfloat16*)p)[i] = __float2bfloat16(v);
  else    ((float*)p)[i] = v;
}
__device__ __forceinline__ unsigned short f2bf(float v) {  // RNE
  unsigned x = __float_as_uint(v);
  return (unsigned short)((x + 0x7FFFu + ((x >> 16) & 1u)) >> 16);
}
__device__ __forceinline__ float sigm(float x) { return 1.f / (1.f + expf(-x)); }

// ---------------------------------------------------------------------------
// k_wprep: transpose MLP weights to k-major bf16 + fold constants. One-time.
// ---------------------------------------------------------------------------
__global__ __launch_bounds__(256)
void k_wprep(const void* W0, const void* W1, const void* W2,
             const void* b1, const void* g0, const void* be0,
             const void* b2, const void* g1, const void* be1,
             float* ws, const void* lnvw)
{
  const bool bf = (((const unsigned*)lnvw)[0] != 0x3F800000u);
  const int b = blockIdx.x, tid = threadIdx.x;
  unsigned short* wt0 = (unsigned short*)(ws + WT0_OFF);
  unsigned short* wt1 = (unsigned short*)(ws + WT1_OFF);
  unsigned short* wt2 = (unsigned short*)(ws + WT2_OFF);
  if (b < 64) {                 // Wt0: 4 k-rows x 512 cols per block
    for (int e = tid; e < 2048; e += 256) {
      const int k = b*4 + (e >> 9), c = e & 511;
      wt0[k*512 + c] = bf ? ((const unsigned short*)W0)[c*256 + k]
                          : f2bf(((const float*)W0)[c*256 + k]);
    }
  } else if (b < 192) {         // Wt1
    for (int e = tid; e < 2048; e += 256) {
      const int k = (b - 64)*4 + (e >> 9), c = e & 511;
      wt1[k*512 + c] = bf ? ((const unsigned short*)W1)[c*512 + k]
                          : f2bf(((const float*)W1)[c*512 + k]);
    }
  } else if (b < 256) {         // Wt2: 8 k-rows x 256 cols
    for (int e = tid; e < 2048; e += 256) {
      const int k = (b - 192)*8 + (e >> 8), c = e & 255;
      wt2[k*256 + c] = bf ? ((const unsigned short*)W2)[c*512 + k]
                          : f2bf(((const float*)W2)[c*512 + k]);
    }
  } else if (b == 256) {        // SwgB[c], btB[c]
    for (int c = tid; c < 512; c += 256) {
      float sg = 0.f, sb = 0.f;
      for (int k = 0; k < 512; ++k) {
        const float w = ldv(W1, c*512 + k, bf);
        sg += w*ldv(g0, k, bf); sb += w*ldv(be0, k, bf);
      }
      (ws + SWGB_OFF)[c] = sg;
      (ws + BTB_OFF)[c] = ldv(b1, c, bf) + sb;
    }
  } else {                      // SwgC[c], btC[c]
    if (tid < 256) {
      float sg = 0.f, sb = 0.f;
      for (int k = 0; k < 512; ++k) {
        const float w = ldv(W2, tid*512 + k, bf);
        sg += w*ldv(g1, k, bf); sb += w*ldv(be1, k, bf);
      }
      (ws + SWGC_OFF)[tid] = sg;
      (ws + BTC_OFF)[tid] = ldv(b2, tid, bf) + sb;
    }
  }
}

// ---------------------------------------------------------------------------
// GRU: 384 threads, thread j owns gate-row j (0..127 r, 128..255 z, 256..383 n)
// ---------------------------------------------------------------------------
template<int INSZ, int TSTEPS>
__device__ void gru_run(const float* xs, int rev,
                        const void* Wih, const void* Whh,
                        const void* bih, const void* bhh,
                        bool bf, float* hout,
                        float* h0, float* h1, float* rz)
{
  const int j = threadIdx.x;
  float whh[128];
  float wih[INSZ];
  if (bf) {
    const unsigned short* wp = (const unsigned short*)Whh;
    #pragma unroll
    for (int k8 = 0; k8 < 16; ++k8) {
      const uint4 q = *(const uint4*)&wp[j*128 + k8*8];
      up2(q.x, &whh[k8*8+0]); up2(q.y, &whh[k8*8+2]);
      up2(q.z, &whh[k8*8+4]); up2(q.w, &whh[k8*8+6]);
    }
    const unsigned short* ip = (const unsigned short*)Wih;
    #pragma unroll
    for (int c2 = 0; c2 < INSZ/2; ++c2) {
      const unsigned u = *(const unsigned*)&ip[j*INSZ + c2*2];
      up2(u, &wih[c2*2]);
    }
  } else {
    const float* wp = (const float*)Whh;
    #pragma unroll
    for (int k4 = 0; k4 < 32; ++k4) {
      const float4 q = *(const float4*)&wp[j*128 + k4*4];
      whh[k4*4+0]=q.x; whh[k4*4+1]=q.y; whh[k4*4+2]=q.z; whh[k4*4+3]=q.w;
    }
    const float* ip = (const float*)Wih;
    #pragma unroll
    for (int c = 0; c < INSZ; ++c) wih[c] = ip[j*INSZ + c];
  }
  const float bi = ldv(bih, j, bf);
  const float bh = ldv(bhh, j, bf);
  if (j < 128) h0[j] = 0.f;
  __syncthreads();

  #pragma unroll 1
  for (int it = 0; it < TSTEPS; ++it) {
    const float* hc = (it & 1) ? h1 : h0;
    float*       hn = (it & 1) ? h0 : h1;
    const int t = rev ? (TSTEPS - 1 - it) : it;
    float gh = bh;
    const float4* h4 = (const float4*)hc;
    #pragma unroll
    for (int k4 = 0; k4 < 32; ++k4) {
      const float4 hv = h4[k4];
      gh += whh[k4*4+0]*hv.x + whh[k4*4+1]*hv.y + whh[k4*4+2]*hv.z + whh[k4*4+3]*hv.w;
    }
    float gi = bi;
    #pragma unroll
    for (int c = 0; c < INSZ; ++c) gi += wih[c] * xs[t*INSZ + c];
    if (j < 256) rz[j] = sigm(gi + gh);      // r (0..127), z (128..255)
    __syncthreads();
    if (j >= 256) {
      const int i = j - 256;
      const float n = tanhf(gi + rz[i]*gh);
      const float z = rz[128 + i];
      hn[i] = (1.f - z)*n + z*hc[i];
    }
    __syncthreads();
  }
  const float* hf = (TSTEPS & 1) ? h1 : h0;
  if (j < 128) hout[j] = hf[j];
}

// Merged encoder+decoder GRU: blocks 0..255 = enc (row, dir), 256..511 = dec.
__global__ __launch_bounds__(384)
void k_gru(const void* cov, const void* trh, const void* outh, const void* trt,
           const void* eWf, const void* eUf, const void* ebf, const void* ecf,
           const void* eWb, const void* eUb, const void* ebb, const void* ecb,
           const void* dWf, const void* dUf, const void* dbf, const void* dcf,
           const void* dWb, const void* dUb, const void* dbb, const void* dcb,
           float* ws, const void* lnvw)
{
  __shared__ __align__(16) float xs[NLH*28];
  __shared__ __align__(16) float h0[128], h1[128];
  __shared__ float rz[256];
  __shared__ float sm_[28], ss_[28];
  const bool bf = (((const unsigned*)lnvw)[0] != 0x3F800000u);
  const int bid = blockIdx.x;
  const int tid = threadIdx.x;

  if (bid < 256) {  // ---- encoder ----
    const int row = bid >> 1, back = bid & 1;
    if (tid < 28) {
      const void* src; int w; int f2;
      if (tid < 16)      { src = cov;  w = 16; f2 = tid; }
      else if (tid < 24) { src = trh;  w = 8;  f2 = tid - 16; }
      else               { src = outh; w = 4;  f2 = tid - 24; }
      float s1 = 0.f, s2 = 0.f;
      for (int t = 0; t < NLH; ++t) {
        const float v = ldv(src, (row*NLH + t)*w + f2, bf);
        s1 += v; s2 += v*v;
      }
      const float m = s1 / NLH;
      const float var = s2 / NLH - m*m;
      sm_[tid] = m;
      ss_[tid] = sqrtf(fmaxf(var, 0.f)) + EPS;
    }
    __syncthreads();
    for (int e = tid; e < NLH*28; e += 384) {
      const int t = e / 28, f2 = e % 28;
      const void* src; int w; int ff;
      if (f2 < 16)      { src = cov;  w = 16; ff = f2; }
      else if (f2 < 24) { src = trh;  w = 8;  ff = f2 - 16; }
      else              { src = outh; w = 4;  ff = f2 - 24; }
      const float v = ldv(src, (row*NLH + t)*w + ff, bf);
      xs[e] = (v - sm_[f2]) / ss_[f2];
    }
    __syncthreads();
    float* hout = ws + WSH_OFF + (row*4 + back)*128;
    if (back == 0) gru_run<28, NLH>(xs, 0, eWf, eUf, ebf, ecf, bf, hout, h0, h1, rz);
    else           gru_run<28, NLH>(xs, 1, eWb, eUb, ebb, ecb, bf, hout, h0, h1, rz);
  } else {          // ---- decoder ----
    const int b2 = bid - 256;
    const int row = b2 >> 1, back = b2 & 1;
    if (tid < 8) {
      float s1 = 0.f, s2 = 0.f;
      for (int t = 0; t < NLH; ++t) {
        const float v = ldv(trh, (row*NLH + t)*8 + tid, bf);
        s1 += v; s2 += v*v;
      }
      const float m = s1 / NLH;
      const float var = s2 / NLH - m*m;
      sm_[tid] = m;
      ss_[tid] = sqrtf(fmaxf(var, 0.f)) + EPS;
    }
    __syncthreads();
    for (int e = tid; e < NLP*8; e += 384) {
      const int t = e >> 3, f2 = e & 7;
      const float v = ldv(trt, (row*NLP + t)*8 + f2, bf);
      xs[e] = (v - sm_[f2]) / ss_[f2];
    }
    __syncthreads();
    float* hout = ws + WSH_OFF + (row*4 + 2 + back)*128;
    if (back == 0) gru_run<8, NLP>(xs, 0, dWf, dUf, dbf, dcf, bf, hout, h0, h1, rz);
    else           gru_run<8, NLP>(xs, 1, dWb, dUb, dbb, dcb, bf, hout, h0, h1, rz);
  }
}

// ---------------------------------------------------------------------------
// SDE: 64 WGs x 1024 threads, 2 rows/WG, weights streamed k-major from L2.
// ---------------------------------------------------------------------------
// One layer: out[2][N] = tanh(fold(in[2][K] @ Wt^T)). Thread = (col-quad
// cq = tid>>LKS, k-slice ks = tid & (KS-1)). SM = bank-stagger multiplier.
template<int K, int N, int LKS, int SM, int FOLD>
__device__ __forceinline__ void mm(
    const float* in,            // LDS [2][K]
    const unsigned short* Wt,   // global k-major [K][N]
    const float* btot, const float* Swg, const float* gsc,
    float* out,                 // LDS [2][N]
    float* red, float* mrow, float* rsrow)
{
  const int tid = threadIdx.x;
  constexpr int KS = 1 << LKS;
  constexpr int KPT = K / KS;        // k elems per thread
  constexpr int NS = KPT / 4;        // float4 slots
  const int ks = tid & (KS - 1);
  const int c0 = (tid >> LKS) * 4;

  if (FOLD && tid < 2) {             // finalize prev-layer LN stats (width K)
    float s1 = 0.f, s2 = 0.f;
    #pragma unroll
    for (int wv = 0; wv < 16; ++wv) {
      s1 += red[wv*4 + tid*2 + 0];
      s2 += red[wv*4 + tid*2 + 1];
    }
    const float m = s1 / (float)K;
    const float var = s2 / (float)K - m*m;
    mrow[tid] = m;
    rsrow[tid] = rsqrtf(var + EPS);
  }

  float a0[4] = {0.f,0.f,0.f,0.f}, a1[4] = {0.f,0.f,0.f,0.f};
  #pragma unroll
  for (int s = 0; s < NS; ++s) {
    const int kk4 = (s + ks*SM) & (NS - 1);
    const int k0 = ks*KPT + kk4*4;
    const float4 x0 = *(const float4*)(in + k0);
    const float4 x1 = *(const float4*)(in + K + k0);
    #pragma unroll
    for (int q = 0; q < 4; ++q) {
      const ushort4 w4 = *(const ushort4*)(Wt + (k0 + q)*N + c0);
      const float xq0 = q==0?x0.x:q==1?x0.y:q==2?x0.z:x0.w;
      const float xq1 = q==0?x1.x:q==1?x1.y:q==2?x1.z:x1.w;
      const float w0 = bf2f(w4.x), w1 = bf2f(w4.y), w2 = bf2f(w4.z), w3 = bf2f(w4.w);
      a0[0] += w0*xq0; a0[1] += w1*xq0; a0[2] += w2*xq0; a0[3] += w3*xq0;
      a1[0] += w0*xq1; a1[1] += w1*xq1; a1[2] += w2*xq1; a1[3] += w3*xq1;
    }
  }
  #pragma unroll
  for (int mk = 1; mk < KS; mk <<= 1) {
    #pragma unroll
    for (int j = 0; j < 4; ++j) {
      a0[j] += __shfl_xor(a0[j], mk, 64);
      a1[j] += __shfl_xor(a1[j], mk, 64);
    }
  }
  __syncthreads();   // FOLD: mrow/rsrow visible; also orders red reuse

  float t0[4], t1[4];
  #pragma unroll
  for (int j = 0; j < 4; ++j) {
    float p0, p1;
    if (FOLD) {
      const float sw = Swg[c0 + j], bt = btot[c0 + j];
      p0 = rsrow[0]*(a0[j] - mrow[0]*sw) + bt;
      p1 = rsrow[1]*(a1[j] - mrow[1]*sw) + bt;
    } else {
      p0 = a0[j] + btot[c0 + j];
      p1 = a1[j] + btot[c0 + j];
    }
    t0[j] = tanhf(p0);
    t1[j] = tanhf(p1);
  }
  if (ks == 0) {
    float4 o0, o1;
    if (gsc) {
      o0 = make_float4(gsc[c0]*t0[0], gsc[c0+1]*t0[1], gsc[c0+2]*t0[2], gsc[c0+3]*t0[3]);
      o1 = make_float4(gsc[c0]*t1[0], gsc[c0+1]*t1[1], gsc[c0+2]*t1[2], gsc[c0+3]*t1[3]);
    } else {
      o0 = make_float4(t0[0], t0[1], t0[2], t0[3]);
      o1 = make_float4(t1[0], t1[1], t1[2], t1[3]);
    }
    *(float4*)(out + c0) = o0;
    *(float4*)(out + N + c0) = o1;
  }
  // raw-tanh stats: full-wave butterfly (ks-duplicates folded out by 1/KS)
  float s10 = t0[0]+t0[1]+t0[2]+t0[3];
  float s20 = t0[0]*t0[0]+t0[1]*t0[1]+t0[2]*t0[2]+t0[3]*t0[3];
  float s11 = t1[0]+t1[1]+t1[2]+t1[3];
  float s21 = t1[0]*t1[0]+t1[1]*t1[1]+t1[2]*t1[2]+t1[3]*t1[3];
  #pragma unroll
  for (int mk = 1; mk < 64; mk <<= 1) {
    s10 += __shfl_xor(s10, mk, 64);
    s20 += __shfl_xor(s20, mk, 64);
    s11 += __shfl_xor(s11, mk, 64);
    s21 += __shfl_xor(s21, mk, 64);
  }
  if ((tid & 63) == 0) {
    const float inv = 1.0f / (float)KS;
    const int wv = tid >> 6;
    red[wv*4 + 0] = s10*inv; red[wv*4 + 1] = s20*inv;
    red[wv*4 + 2] = s11*inv; red[wv*4 + 3] = s21*inv;
  }
}

__global__ __launch_bounds__(1024, 1)
void k_sde(float* ws,
           const void* b0, const void* g0,
           const void* g1, const void* g2, const void* be2,
           const void* noise, const void* lnvw)
{
  __shared__ __align__(16) float st[2*256];
  __shared__ __align__(16) float bufA[2*512];
  __shared__ __align__(16) float bufB[2*512];
  __shared__ __align__(16) float bufC[2*256];
  __shared__ float gl0[512], gl1[512], gCl[256], beCl[256];
  __shared__ float btA[512], SwgB[512], btB[512], SwgC[256], btC[256];
  __shared__ float red[64], redE[8];
  __shared__ float mrow[2], rsrow[2], lacc[2];

  const bool bf = (((const unsigned*)lnvw)[0] != 0x3F800000u);
  const int tid  = threadIdx.x;
  const int rowg = blockIdx.x;      // 0..63, rows 2*rowg, 2*rowg+1

  if (tid < 512) {
    gl0[tid] = ldv(g0, tid, bf);
    gl1[tid] = ldv(g1, tid, bf);
    btA[tid] = ldv(b0, tid, bf);
    SwgB[tid] = (ws + SWGB_OFF)[tid];
    btB[tid]  = (ws + BTB_OFF)[tid];
  } else if (tid < 768) {
    const int c = tid - 512;
    gCl[c] = ldv(g2, c, bf); beCl[c] = ldv(be2, c, bf);
    SwgC[c] = (ws + SWGC_OFF)[c];
    btC[c]  = (ws + BTC_OFF)[c];
  }

  // x0 = [0.5*(enc_f+enc_b), 0.5*(dec_f+dec_b)] for this WG's 2 rows.
  const float* wsh = ws + WSH_OFF;
  if (tid < 512) {
    const int r = tid >> 8, d = tid & 255;
    const int row = rowg*2 + r;
    float v;
    if (d < 128) v = 0.5f*(wsh[(row*4 + 0)*128 + d]         + wsh[(row*4 + 1)*128 + d]);
    else         v = 0.5f*(wsh[(row*4 + 2)*128 + (d - 128)] + wsh[(row*4 + 3)*128 + (d - 128)]);
    st[tid] = v;
  }
  if (tid < 2) lacc[tid] = 0.f;
  __syncthreads();
  float* ysw = ws + YS_OFF;
  if (tid < 2*257) {   // sample 0 = aug0
    const int rr = tid / 257, d = tid % 257;
    ysw[((rowg*2 + rr)*8 + 0)*257 + d] = (d < 256) ? st[rr*256 + d] : 0.f;
  }
  __syncthreads();

  const unsigned short* wt0 = (const unsigned short*)(ws + WT0_OFF);
  const unsigned short* wt1 = (const unsigned short*)(ws + WT1_OFF);
  const unsigned short* wt2 = (const unsigned short*)(ws + WT2_OFF);

  #pragma unroll 1
  for (int s = 0; s < NSTEP; ++s) {
    // prefetch this step's noise (1 elem/thread for tid<512)
    float nz = 0.f;
    if (tid < 512) {
      const int r = tid >> 8, d = tid & 255;
      const int nb = ((s*NB) + rowg*2 + r)*256 + d;
      nz = ldv(noise, nb, bf);
    }

    // L0: 256 -> 512 (no fold)
    mm<256,512,3,1,0>(st, wt0, btA, nullptr, gl0, bufA, red, mrow, rsrow);
    __syncthreads();
    // L1: 512 -> 512 (fold LN0)
    mm<512,512,3,2,1>(bufA, wt1, btB, SwgB, gl1, bufB, red, mrow, rsrow);
    __syncthreads();
    // L2: 512 -> 256 (fold LN1), raw tanh out
    mm<512,256,4,1,1>(bufB, wt2, btC, SwgC, nullptr, bufC, red, mrow, rsrow);
    __syncthreads();

    // finalize C stats
    if (tid < 2) {
      float s1 = 0.f, s2 = 0.f;
      #pragma unroll
      for (int wv = 0; wv < 16; ++wv) {
        s1 += red[wv*4 + tid*2 + 0];
        s2 += red[wv*4 + tid*2 + 1];
      }
      const float m = s1 / 256.f;
      const float var = s2 / 256.f - m*m;
      mrow[tid] = m;
      rsrow[tid] = rsqrtf(var + EPS);
    }
    __syncthreads();

    // Euler + flq (LN-C affine inline)
    if (tid < 512) {
      const int r = tid >> 8, d = tid & 255;
      const float m = mrow[r], rs = rsrow[r];
      const float f = (bufC[r*256 + d] - m)*rs*gCl[d] + beCl[d];
      const float ys = st[r*256 + d];
      const float uu = f + ys;                 // u = 2*(f+ys); scale later
      float u2 = uu*uu;
      st[r*256 + d] = ys + f*DT_ + SIG_*SQDT_*nz;
      #pragma unroll
      for (int mk = 1; mk < 64; mk <<= 1) u2 += __shfl_xor(u2, mk, 64);
      if ((tid & 63) == 0) redE[tid >> 6] = u2;
    }
    __syncthreads();
    if (tid < 2)
      lacc[tid] += 2.f*(redE[tid*4+0] + redE[tid*4+1] + redE[tid*4+2] + redE[tid*4+3])*DT_;
    __syncthreads();

    if (((s + 1) % NSUB) == 0) {
      const int smp = (s + 1)/NSUB;
      if (tid < 2*257) {
        const int rr = tid / 257, d = tid % 257;
        ysw[((rowg*2 + rr)*8 + smp)*257 + d] = (d < 256) ? st[rr*256 + d] : lacc[rr];
      }
      __syncthreads();
    }
  }
}

// ---------------------------------------------------------------------------
// Epilogue: decoder head + output packing (mu | var | logqp)
// ---------------------------------------------------------------------------
__global__ __launch_bounds__(128)
void k_epi(const float* ws, const void* outh,
           const void* outW, const void* outB,
           const void* lvw, const void* lvb,
           void* d_out)
{
  __shared__ __align__(16) float ysl[8*257];
  __shared__ __align__(16) float ow[8*128];
  __shared__ float dout[64];
  __shared__ float om4[4], os4[4], vmv[4], vrs[4], ob[8], lw[4], lb[4];
  const bool bf = (((const unsigned*)lvw)[0] != 0x3F800000u);
  const int row = blockIdx.x, tid = threadIdx.x;
  const float* ysw = ws + YS_OFF + row*(8*257);
  for (int e = tid; e < 8*257; e += 128) ysl[e] = ysw[e];
  for (int e = tid; e < 1024; e += 128)  ow[e]  = ldv(outW, e, bf);
  if (tid < 8) ob[tid] = ldv(outB, tid, bf);
  if (tid < 4) { lw[tid] = ldv(lvw, tid, bf); lb[tid] = ldv(lvb, tid, bf); }
  if (tid < 4) {
    float s1 = 0.f, s2 = 0.f;
    for (int t = 0; t < NLH; ++t) {
      const float v = ldv(outh, (row*NLH + t)*4 + tid, bf);
      s1 += v; s2 += v*v;
    }
    const float m = s1 / NLH;
    const float var = s2 / NLH - m*m;
    om4[tid] = m;
    os4[tid] = sqrtf(fmaxf(var, 0.f)) + EPS;
  }
  __syncthreads();
  if (tid < 64) {
    const int smp = tid >> 3, o = tid & 7;
    float a = ob[o];
    #pragma unroll
    for (int k = 0; k < 128; ++k) a += ysl[smp*257 + k]*ow[o*128 + k];
    dout[smp*8 + o] = a;
  }
  __syncthreads();
  if (tid < 4) {
    float s1 = 0.f, s2 = 0.f;
    #pragma unroll
    for (int smp = 0; smp < 8; ++smp) { const float v = dout[smp*8 + 4 + tid]; s1 += v; s2 += v*v; }
    const float m = s1 / 8.f;
    const float var = s2 / 8.f - m*m;
    vmv[tid] = m;
    vrs[tid] = rsqrtf(var + EPS);
  }
  __syncthreads();
  if (tid < 32) {
    const int smp = tid >> 2, j = tid & 3;
    const float mu = dout[smp*8 + j]*os4[j] + om4[j];
    st_out(d_out, (row*8 + smp)*4 + j, mu, bf);
    const float vo = dout[smp*8 + 4 + j];
    const float vr = sigm((vo - vmv[j])*vrs[j]*lw[j] + lb[j]);
    st_out(d_out, 4096 + (row*8 + smp)*4 + j, vr, bf);
  }
  for (int e = tid; e < 129*8; e += 128) {
    const int j = e >> 3, smp = e & 7;
    st_out(d_out, 8192 + (row*129 + j)*8 + smp, ysl[smp*257 + 128 + j], bf);
  }
}

// ---------------------------------------------------------------------------
extern "C" void kernel_launch(void* const* d_in, const int* in_sizes, int n_in,
                              void* d_out, int out_size, void* d_ws, size_t ws_size,
                              hipStream_t stream) {
  (void)in_sizes; (void)n_in; (void)out_size; (void)ws_size;
  float* ws = (float*)d_ws;
  const void* lnvw = d_in[35];

  k_wprep<<<258, 256, 0, stream>>>(
      d_in[21], d_in[25], d_in[29],
      d_in[26], d_in[23], d_in[24],
      d_in[30], d_in[27], d_in[28],
      ws, lnvw);
  k_gru<<<512, 384, 0, stream>>>(
      d_in[0], d_in[1], d_in[2], d_in[3],
      d_in[5], d_in[6], d_in[7], d_in[8],
      d_in[9], d_in[10], d_in[11], d_in[12],
      d_in[13], d_in[14], d_in[15], d_in[16],
      d_in[17], d_in[18], d_in[19], d_in[20],
      ws, lnvw);
  k_sde<<<64, 1024, 0, stream>>>(
      ws,
      d_in[22], d_in[23],
      d_in[27], d_in[31], d_in[32],
      d_in[37], lnvw);
  k_epi<<<128, 128, 0, stream>>>(
      (const float*)d_ws, d_in[2],
      d_in[33], d_in[34], d_in[35], d_in[36],
      d_out);
}